// Round 5
// baseline (327.409 us; speedup 1.0000x reference)
//
#include <hip/hip_runtime.h>

// BeliefUpdate: b_{t+1} = normalize((b_t+eps) * W), W = (lik+eps)(m0+eps)(m1+eps)
//   => b_t = normalize(b_0 * W^t)  (inner +eps dropped: ~2.6e-8 rel err/iter)
// R5 = R1 (best: short blocks, 32-lane row groups, DPP row-reduce, rcpf, NT
// stores) minus structural overhead:
//  - no LDS / __syncthreads: per-wave 64-lane reduce of chg[9] + 9 spread
//    atomics from lane 0
//  - finalize merged into phaseC (3 dispatches total)
// R2/R4 persistent/prefetch variants regressed (spill; L3-residency loss) --
// documented dead ends, do not revisit.

typedef float f32x4 __attribute__((ext_vector_type(4)));

static constexpr int   kD      = 256;
static constexpr float kEps    = 1e-10f;
static constexpr float kThresh = 1e-4f;
static constexpr int   kIters  = 10;
static constexpr int   kSlots  = 64;

template<int CTRL>
__device__ __forceinline__ float dpp_add(float v) {
    int t = __builtin_amdgcn_update_dpp(0, __float_as_int(v), CTRL, 0xf, 0xf, true);
    return v + __int_as_float(t);
}
template<int CTRL>
__device__ __forceinline__ float dpp_max(float v) {
    int t = __builtin_amdgcn_update_dpp(0, __float_as_int(v), CTRL, 0xf, 0xf, true);
    return fmaxf(v, __int_as_float(t));
}
__device__ __forceinline__ float swz_xor16(float v) {
    return __int_as_float(__builtin_amdgcn_ds_swizzle(__float_as_int(v), 0x401F));
}

__global__ __launch_bounds__(64) void bu_init(unsigned* __restrict__ slots) {
    if (threadIdx.x < (kIters - 1) * kSlots / 9) { }  // (kept simple below)
    for (int i = threadIdx.x; i < (kIters - 1) * kSlots; i += 64) slots[i] = 0u;
}

// 256 threads = 4 waves; each wave = two 32-lane row groups (8 elems/lane).
__global__ __launch_bounds__(256) void bu_main(
    const float* __restrict__ prior,
    const float* __restrict__ lik,
    const float* __restrict__ msg,
    float* __restrict__ belief,
    unsigned* __restrict__ slots,
    int B)
{
    const int tid  = threadIdx.x;
    const int wave = tid >> 6;
    const int lane = tid & 63;
    const int sub  = lane >> 5;        // which row of the wave's pair
    const int q    = lane & 31;        // position within 32-lane row group
    const int wid  = blockIdx.x * 4 + wave;
    const int row  = wid * 2 + sub;
    const size_t off = (size_t)row * kD + (size_t)q * 8;

    const f32x4* pb = (const f32x4*)(prior + off);
    const f32x4* pl = (const f32x4*)(lik + off);
    const f32x4* p0 = (const f32x4*)(msg + off);
    const f32x4* p1 = (const f32x4*)(msg + (size_t)B * kD + off);

    f32x4 vb0 = pb[0], vb1 = pb[1];
    f32x4 vl0 = pl[0], vl1 = pl[1];
    f32x4 va0 = p0[0], va1 = p0[1];
    f32x4 vc0 = p1[0], vc1 = p1[1];

    float u[8], W[8], pv[8];
    #pragma unroll
    for (int k = 0; k < 4; ++k) {
        u[k]     = vb0[k];
        u[4 + k] = vb1[k];
        W[k]     = (vl0[k] + kEps) * (va0[k] + kEps) * (vc0[k] + kEps);
        W[4 + k] = (vl1[k] + kEps) * (va1[k] + kEps) * (vc1[k] + kEps);
        pv[k]     = u[k];
        pv[4 + k] = u[4 + k];
    }

    float chg[kIters - 1];
    #pragma unroll
    for (int t = 0; t < kIters; ++t) {
        #pragma unroll
        for (int j = 0; j < 8; ++j) u[j] *= W[j];
        float s = ((u[0] + u[1]) + (u[2] + u[3])) + ((u[4] + u[5]) + (u[6] + u[7]));
        s = dpp_add<0x121>(s);   // row_ror:1
        s = dpp_add<0x122>(s);   // row_ror:2
        s = dpp_add<0x124>(s);   // row_ror:4
        s = dpp_add<0x128>(s);   // row_ror:8 -> 16-lane sum
        s += swz_xor16(s);       // -> 32-lane row sum
        const float inv = __builtin_amdgcn_rcpf(s);
        if (t < kIters - 1) {
            float c = 0.f;
            #pragma unroll
            for (int j = 0; j < 8; ++j) {
                float nb = u[j] * inv;
                c = fmaxf(c, fabsf(nb - pv[j]));
                pv[j] = nb;
            }
            chg[t] = c;
        } else {
            #pragma unroll
            for (int j = 0; j < 8; ++j) pv[j] = u[j] * inv;
        }
    }

    // b_10 out (NT: keep L3 for the re-read inputs)
    f32x4 o0 = {pv[0], pv[1], pv[2], pv[3]};
    f32x4 o1 = {pv[4], pv[5], pv[6], pv[7]};
    __builtin_nontemporal_store(o0, (f32x4*)(belief + off));
    __builtin_nontemporal_store(o1, (f32x4*)(belief + off) + 1);

    // per-wave 64-lane reduce of chg[0..8]; lane 0 -> 9 spread atomics
    #pragma unroll
    for (int t = 0; t < kIters - 1; ++t) {
        float v = chg[t];
        v = dpp_max<0x121>(v);
        v = dpp_max<0x122>(v);
        v = dpp_max<0x124>(v);
        v = dpp_max<0x128>(v);
        v = fmaxf(v, swz_xor16(v));
        v = fmaxf(v, __shfl_xor(v, 32));
        chg[t] = v;
    }
    if (lane == 0) {
        #pragma unroll
        for (int t = 0; t < kIters - 1; ++t)
            atomicMax(&slots[t * kSlots + (wid & (kSlots - 1))],
                      __float_as_uint(chg[t]));
    }
}

// Merged finalize + rare-path recompute. Every block derives iters from slots;
// block 0 writes iters_out; if converged early (a.s. never for these inputs),
// all blocks recompute b_k with the eps-exact iteration.
__global__ __launch_bounds__(256) void bu_finalC(
    const unsigned* __restrict__ slots,
    const float* __restrict__ prior,
    const float* __restrict__ lik,
    const float* __restrict__ msg,
    float* __restrict__ belief,
    float* __restrict__ iters_out,
    int B)
{
    const int lane = threadIdx.x & 63;
    float chg[kIters - 1];
    #pragma unroll
    for (int t = 0; t < kIters - 1; ++t) {
        float v = __uint_as_float(slots[t * kSlots + lane]);
        #pragma unroll
        for (int o = 32; o > 0; o >>= 1) v = fmaxf(v, __shfl_xor(v, o));
        chg[t] = v;   // uniform across the wave now
    }
    int iters = 0;
    {
        bool done = false;
        #pragma unroll
        for (int t = 0; t < kIters; ++t) {
            if (!done) iters++;
            if (t < kIters - 1 && chg[t] < kThresh) done = true;
        }
    }
    if (blockIdx.x == 0 && threadIdx.x == 0) *iters_out = (float)iters;
    if (iters >= kIters) return;   // b_10 already written by bu_main

    const int k    = iters;
    const int wave = threadIdx.x >> 6;
    const int g    = lane >> 4;
    const int q    = lane & 15;
    const int nUnits = B / 16;
    for (int u2 = blockIdx.x; u2 < nUnits; u2 += gridDim.x) {
        const int row = (u2 * 4 + wave) * 4 + g;
        const size_t off = (size_t)row * kD + (size_t)q * 16;
        const float* p0 = prior + off;
        const float* p1 = lik   + off;
        const float* p2 = msg   + off;
        const float* p3 = msg   + (size_t)B * kD + off;
        float b[16], W[16];
        #pragma unroll
        for (int c = 0; c < 4; ++c) {
            float4 vb = *(const float4*)(p0 + 4 * c);
            float4 vl = *(const float4*)(p1 + 4 * c);
            float4 v0 = *(const float4*)(p2 + 4 * c);
            float4 v1 = *(const float4*)(p3 + 4 * c);
            b[4*c+0] = vb.x; b[4*c+1] = vb.y; b[4*c+2] = vb.z; b[4*c+3] = vb.w;
            W[4*c+0] = (vl.x + kEps) * (v0.x + kEps) * (v1.x + kEps);
            W[4*c+1] = (vl.y + kEps) * (v0.y + kEps) * (v1.y + kEps);
            W[4*c+2] = (vl.z + kEps) * (v0.z + kEps) * (v1.z + kEps);
            W[4*c+3] = (vl.w + kEps) * (v0.w + kEps) * (v1.w + kEps);
        }
        for (int t = 0; t < k; ++t) {
            float pp[16];
            float s = 0.f;
            #pragma unroll
            for (int j = 0; j < 16; ++j) { pp[j] = (b[j] + kEps) * W[j]; s += pp[j]; }
            s += __shfl_xor(s, 1);
            s += __shfl_xor(s, 2);
            s += __shfl_xor(s, 4);
            s += __shfl_xor(s, 8);
            const float inv = 1.0f / s;
            #pragma unroll
            for (int j = 0; j < 16; ++j) b[j] = pp[j] * inv;
        }
        float* po = belief + off;
        #pragma unroll
        for (int c = 0; c < 4; ++c)
            *(float4*)(po + 4 * c) = make_float4(b[4*c], b[4*c+1], b[4*c+2], b[4*c+3]);
    }
}

extern "C" void kernel_launch(void* const* d_in, const int* in_sizes, int n_in,
                              void* d_out, int out_size, void* d_ws, size_t ws_size,
                              hipStream_t stream) {
    const float* prior = (const float*)d_in[0];
    const float* lik   = (const float*)d_in[1];
    const float* msg   = (const float*)d_in[2];
    const int B = in_sizes[0] / kD;          // 131072

    float* belief    = (float*)d_out;
    float* iters_out = belief + (size_t)B * kD;

    unsigned* slots = (unsigned*)d_ws;

    bu_init<<<1, 64, 0, stream>>>(slots);
    bu_main<<<B / 8, 256, 0, stream>>>(prior, lik, msg, belief, slots, B);
    bu_finalC<<<256, 256, 0, stream>>>(slots, prior, lik, msg, belief, iters_out, B);
}

// Round 6
// 134.866 us; speedup vs baseline: 2.4277x; 2.4277x over previous
//
#include <hip/hip_runtime.h>

// BeliefUpdate. Key identities:
//   b_{t+1} = softmax(log(b_t+eps) + log_lik) = normalize((b_t+eps) * W),
//   W = (lik+eps)(m0+eps)(m1+eps);  dropping inner +eps (rel err ~2.6e-8/iter):
//   b_10 = normalize(b_0 * W^10)    -- W^10 by squaring, ONE normalization.
// iters needs only, per t in [0,8], a WITNESS row with change >= 1e-4 (a lower
// bound of the global max proves "not converged"). A 4096-row sampled
// trajectory provides witnesses (a.s. for this data); a flag-guarded full
// fallback (R1 clone) preserves exactness otherwise.
// Atomic discipline (R5 lesson): one multi-lane atomic instr per block only;
// per-wave scalar atomic bursts (590K instrs) cost +150us. Do not revisit.

typedef float f32x4 __attribute__((ext_vector_type(4)));

static constexpr int   kD      = 256;
static constexpr float kEps    = 1e-10f;
static constexpr float kThresh = 1e-4f;
static constexpr int   kIters  = 10;
static constexpr int   kSlots  = 64;
static constexpr int   kSampleBlocks = 512;   // 4096 sampled rows

template<int CTRL>
__device__ __forceinline__ float dpp_add(float v) {
    int t = __builtin_amdgcn_update_dpp(0, __float_as_int(v), CTRL, 0xf, 0xf, true);
    return v + __int_as_float(t);
}
template<int CTRL>
__device__ __forceinline__ float dpp_max(float v) {
    int t = __builtin_amdgcn_update_dpp(0, __float_as_int(v), CTRL, 0xf, 0xf, true);
    return fmaxf(v, __int_as_float(t));
}
__device__ __forceinline__ float swz_xor16(float v) {
    return __int_as_float(__builtin_amdgcn_ds_swizzle(__float_as_int(v), 0x401F));
}

// ws layout: [0] int flag; [64B..] slotsW[9*64]; then slotsF[9*64]
__global__ __launch_bounds__(256) void bu_init(unsigned* __restrict__ ws) {
    for (int i = threadIdx.x; i < 16 + 2 * (kIters - 1) * kSlots; i += 256)
        ws[i] = 0u;
}

// ---- K1: sampled trajectory -> witness maxima into slotsW --------------
__global__ __launch_bounds__(256) void bu_sample(
    const float* __restrict__ prior,
    const float* __restrict__ lik,
    const float* __restrict__ msg,
    unsigned* __restrict__ slotsW,
    int B, int stride)
{
    const int tid  = threadIdx.x;
    const int wave = tid >> 6;
    const int lane = tid & 63;
    const int sub  = lane >> 5;
    const int q    = lane & 31;
    const int wid  = blockIdx.x * 4 + wave;
    const int row  = (wid * 2 + sub) * stride;
    if (row >= B) return;
    const size_t off = (size_t)row * kD + (size_t)q * 8;

    const f32x4* pb = (const f32x4*)(prior + off);
    const f32x4* pl = (const f32x4*)(lik + off);
    const f32x4* p0 = (const f32x4*)(msg + off);
    const f32x4* p1 = (const f32x4*)(msg + (size_t)B * kD + off);

    f32x4 vb0 = pb[0], vb1 = pb[1];
    f32x4 vl0 = pl[0], vl1 = pl[1];
    f32x4 va0 = p0[0], va1 = p0[1];
    f32x4 vc0 = p1[0], vc1 = p1[1];

    float u[8], W[8], pv[8];
    #pragma unroll
    for (int k = 0; k < 4; ++k) {
        u[k]     = vb0[k];
        u[4 + k] = vb1[k];
        W[k]     = (vl0[k] + kEps) * (va0[k] + kEps) * (vc0[k] + kEps);
        W[4 + k] = (vl1[k] + kEps) * (va1[k] + kEps) * (vc1[k] + kEps);
        pv[k]     = u[k];
        pv[4 + k] = u[4 + k];
    }

    float chg[kIters - 1];
    #pragma unroll
    for (int t = 0; t < kIters - 1; ++t) {   // only chg[0..8] matter
        #pragma unroll
        for (int j = 0; j < 8; ++j) u[j] *= W[j];
        float s = ((u[0] + u[1]) + (u[2] + u[3])) + ((u[4] + u[5]) + (u[6] + u[7]));
        s = dpp_add<0x121>(s);
        s = dpp_add<0x122>(s);
        s = dpp_add<0x124>(s);
        s = dpp_add<0x128>(s);
        s += swz_xor16(s);
        const float inv = __builtin_amdgcn_rcpf(s);
        float c = 0.f;
        #pragma unroll
        for (int j = 0; j < 8; ++j) {
            float nb = u[j] * inv;
            c = fmaxf(c, fabsf(nb - pv[j]));
            pv[j] = nb;
        }
        chg[t] = c;
    }

    #pragma unroll
    for (int t = 0; t < kIters - 1; ++t) {
        float v = chg[t];
        v = dpp_max<0x121>(v);
        v = dpp_max<0x122>(v);
        v = dpp_max<0x124>(v);
        v = dpp_max<0x128>(v);
        v = fmaxf(v, swz_xor16(v));
        chg[t] = v;
    }
    __shared__ float schg[4][2][kIters - 1];
    if (q == 0) {
        #pragma unroll
        for (int t = 0; t < kIters - 1; ++t) schg[wave][sub][t] = chg[t];
    }
    __syncthreads();
    if (tid < kIters - 1) {
        float m = 0.f;
        #pragma unroll
        for (int w2 = 0; w2 < 4; ++w2) {
            m = fmaxf(m, schg[w2][0][tid]);
            m = fmaxf(m, schg[w2][1][tid]);
        }
        atomicMax(&slotsW[tid * kSlots + (blockIdx.x & (kSlots - 1))],
                  __float_as_uint(m));
    }
}

// ---- K2: the 90% kernel -- b10 = normalize(b0 * W^10), pure stream -----
__global__ __launch_bounds__(256) void bu_fast(
    const float* __restrict__ prior,
    const float* __restrict__ lik,
    const float* __restrict__ msg,
    float* __restrict__ belief,
    int B)
{
    const int tid  = threadIdx.x;
    const int wave = tid >> 6;
    const int lane = tid & 63;
    const int sub  = lane >> 5;
    const int q    = lane & 31;
    const int row  = (blockIdx.x * 4 + wave) * 2 + sub;
    const size_t off = (size_t)row * kD + (size_t)q * 8;

    const f32x4* pb = (const f32x4*)(prior + off);
    const f32x4* pl = (const f32x4*)(lik + off);
    const f32x4* p0 = (const f32x4*)(msg + off);
    const f32x4* p1 = (const f32x4*)(msg + (size_t)B * kD + off);

    f32x4 vb0 = pb[0], vb1 = pb[1];
    f32x4 vl0 = pl[0], vl1 = pl[1];
    f32x4 va0 = p0[0], va1 = p0[1];
    f32x4 vc0 = p1[0], vc1 = p1[1];

    float u[8];
    #pragma unroll
    for (int k = 0; k < 4; ++k) {
        float W0 = (vl0[k] + kEps) * (va0[k] + kEps) * (vc0[k] + kEps);
        float W2 = W0 * W0, W4 = W2 * W2, W8 = W4 * W4;
        u[k] = vb0[k] * (W8 * W2);
        float X0 = (vl1[k] + kEps) * (va1[k] + kEps) * (vc1[k] + kEps);
        float X2 = X0 * X0, X4 = X2 * X2, X8 = X4 * X4;
        u[4 + k] = vb1[k] * (X8 * X2);
    }
    float s = ((u[0] + u[1]) + (u[2] + u[3])) + ((u[4] + u[5]) + (u[6] + u[7]));
    s = dpp_add<0x121>(s);
    s = dpp_add<0x122>(s);
    s = dpp_add<0x124>(s);
    s = dpp_add<0x128>(s);
    s += swz_xor16(s);
    const float inv = __builtin_amdgcn_rcpf(s);

    f32x4 o0 = {u[0] * inv, u[1] * inv, u[2] * inv, u[3] * inv};
    f32x4 o1 = {u[4] * inv, u[5] * inv, u[6] * inv, u[7] * inv};
    __builtin_nontemporal_store(o0, (f32x4*)(belief + off));
    __builtin_nontemporal_store(o1, (f32x4*)(belief + off) + 1);
}

// ---- K3: decide from witnesses ----------------------------------------
__global__ __launch_bounds__(64) void bu_resolve(
    const unsigned* __restrict__ slotsW,
    float* __restrict__ iters_out,
    int* __restrict__ flag)
{
    const int lane = threadIdx.x & 63;
    bool allBig = true;
    #pragma unroll
    for (int t = 0; t < kIters - 1; ++t) {
        float v = __uint_as_float(slotsW[t * kSlots + lane]);
        #pragma unroll
        for (int o = 32; o > 0; o >>= 1) v = fmaxf(v, __shfl_xor(v, o));
        allBig = allBig && (v >= kThresh);
    }
    if (threadIdx.x == 0) {
        if (allBig) { *iters_out = (float)kIters; *flag = 0; }
        else        { *flag = 1; }
    }
}

// ---- K4: guarded full fallback (exact trajectory over all rows) --------
__global__ __launch_bounds__(256) void bu_full(
    const float* __restrict__ prior,
    const float* __restrict__ lik,
    const float* __restrict__ msg,
    float* __restrict__ belief,
    unsigned* __restrict__ slotsF,
    const int* __restrict__ flag,
    int B)
{
    if (*flag == 0) return;
    const int tid  = threadIdx.x;
    const int wave = tid >> 6;
    const int lane = tid & 63;
    const int sub  = lane >> 5;
    const int q    = lane & 31;
    const int nUnits = B / 8;
    for (int unit = blockIdx.x; unit < nUnits; unit += gridDim.x) {
        const int row = (unit * 4 + wave) * 2 + sub;
        const size_t off = (size_t)row * kD + (size_t)q * 8;
        const f32x4* pb = (const f32x4*)(prior + off);
        const f32x4* pl = (const f32x4*)(lik + off);
        const f32x4* p0 = (const f32x4*)(msg + off);
        const f32x4* p1 = (const f32x4*)(msg + (size_t)B * kD + off);
        f32x4 vb0 = pb[0], vb1 = pb[1];
        f32x4 vl0 = pl[0], vl1 = pl[1];
        f32x4 va0 = p0[0], va1 = p0[1];
        f32x4 vc0 = p1[0], vc1 = p1[1];
        float u[8], W[8], pv[8];
        #pragma unroll
        for (int k = 0; k < 4; ++k) {
            u[k]     = vb0[k];
            u[4 + k] = vb1[k];
            W[k]     = (vl0[k] + kEps) * (va0[k] + kEps) * (vc0[k] + kEps);
            W[4 + k] = (vl1[k] + kEps) * (va1[k] + kEps) * (vc1[k] + kEps);
            pv[k]     = u[k];
            pv[4 + k] = u[4 + k];
        }
        float chg[kIters - 1];
        #pragma unroll
        for (int t = 0; t < kIters; ++t) {
            #pragma unroll
            for (int j = 0; j < 8; ++j) u[j] *= W[j];
            float s = ((u[0] + u[1]) + (u[2] + u[3])) + ((u[4] + u[5]) + (u[6] + u[7]));
            s = dpp_add<0x121>(s);
            s = dpp_add<0x122>(s);
            s = dpp_add<0x124>(s);
            s = dpp_add<0x128>(s);
            s += swz_xor16(s);
            const float inv = __builtin_amdgcn_rcpf(s);
            if (t < kIters - 1) {
                float c = 0.f;
                #pragma unroll
                for (int j = 0; j < 8; ++j) {
                    float nb = u[j] * inv;
                    c = fmaxf(c, fabsf(nb - pv[j]));
                    pv[j] = nb;
                }
                chg[t] = c;
            } else {
                #pragma unroll
                for (int j = 0; j < 8; ++j) pv[j] = u[j] * inv;
            }
        }
        f32x4 o0 = {pv[0], pv[1], pv[2], pv[3]};
        f32x4 o1 = {pv[4], pv[5], pv[6], pv[7]};
        __builtin_nontemporal_store(o0, (f32x4*)(belief + off));
        __builtin_nontemporal_store(o1, (f32x4*)(belief + off) + 1);

        #pragma unroll
        for (int t = 0; t < kIters - 1; ++t) {
            float v = chg[t];
            v = dpp_max<0x121>(v);
            v = dpp_max<0x122>(v);
            v = dpp_max<0x124>(v);
            v = dpp_max<0x128>(v);
            v = fmaxf(v, swz_xor16(v));
            v = fmaxf(v, __shfl_xor(v, 32));
            chg[t] = v;
        }
        __shared__ float schg[4][kIters - 1];
        if (lane == 0) {
            #pragma unroll
            for (int t = 0; t < kIters - 1; ++t) schg[wave][t] = chg[t];
        }
        __syncthreads();
        if (tid < kIters - 1) {
            float m = fmaxf(fmaxf(schg[0][tid], schg[1][tid]),
                            fmaxf(schg[2][tid], schg[3][tid]));
            atomicMax(&slotsF[tid * kSlots + (unit & (kSlots - 1))],
                      __float_as_uint(m));
        }
        __syncthreads();
    }
}

// ---- K5: guarded exact finalize + rare b_k recompute -------------------
__global__ __launch_bounds__(256) void bu_fin(
    const unsigned* __restrict__ slotsF,
    const float* __restrict__ prior,
    const float* __restrict__ lik,
    const float* __restrict__ msg,
    float* __restrict__ belief,
    float* __restrict__ iters_out,
    const int* __restrict__ flag,
    int B)
{
    if (*flag == 0) return;
    const int lane = threadIdx.x & 63;
    float chg[kIters - 1];
    #pragma unroll
    for (int t = 0; t < kIters - 1; ++t) {
        float v = __uint_as_float(slotsF[t * kSlots + lane]);
        #pragma unroll
        for (int o = 32; o > 0; o >>= 1) v = fmaxf(v, __shfl_xor(v, o));
        chg[t] = v;
    }
    int iters = 0;
    {
        bool done = false;
        #pragma unroll
        for (int t = 0; t < kIters; ++t) {
            if (!done) iters++;
            if (t < kIters - 1 && chg[t] < kThresh) done = true;
        }
    }
    if (blockIdx.x == 0 && threadIdx.x == 0) *iters_out = (float)iters;
    if (iters >= kIters) return;

    const int k    = iters;
    const int wave = threadIdx.x >> 6;
    const int g    = lane >> 4;
    const int q    = lane & 15;
    const int nUnits = B / 16;
    for (int u2 = blockIdx.x; u2 < nUnits; u2 += gridDim.x) {
        const int row = (u2 * 4 + wave) * 4 + g;
        const size_t off = (size_t)row * kD + (size_t)q * 16;
        const float* p0 = prior + off;
        const float* p1 = lik   + off;
        const float* p2 = msg   + off;
        const float* p3 = msg   + (size_t)B * kD + off;
        float b[16], W[16];
        #pragma unroll
        for (int c = 0; c < 4; ++c) {
            float4 vb = *(const float4*)(p0 + 4 * c);
            float4 vl = *(const float4*)(p1 + 4 * c);
            float4 v0 = *(const float4*)(p2 + 4 * c);
            float4 v1 = *(const float4*)(p3 + 4 * c);
            b[4*c+0] = vb.x; b[4*c+1] = vb.y; b[4*c+2] = vb.z; b[4*c+3] = vb.w;
            W[4*c+0] = (vl.x + kEps) * (v0.x + kEps) * (v1.x + kEps);
            W[4*c+1] = (vl.y + kEps) * (v0.y + kEps) * (v1.y + kEps);
            W[4*c+2] = (vl.z + kEps) * (v0.z + kEps) * (v1.z + kEps);
            W[4*c+3] = (vl.w + kEps) * (v0.w + kEps) * (v1.w + kEps);
        }
        for (int t = 0; t < k; ++t) {
            float pp[16];
            float s = 0.f;
            #pragma unroll
            for (int j = 0; j < 16; ++j) { pp[j] = (b[j] + kEps) * W[j]; s += pp[j]; }
            s += __shfl_xor(s, 1);
            s += __shfl_xor(s, 2);
            s += __shfl_xor(s, 4);
            s += __shfl_xor(s, 8);
            const float inv = 1.0f / s;
            #pragma unroll
            for (int j = 0; j < 16; ++j) b[j] = pp[j] * inv;
        }
        float* po = belief + off;
        #pragma unroll
        for (int c = 0; c < 4; ++c)
            *(float4*)(po + 4 * c) = make_float4(b[4*c], b[4*c+1], b[4*c+2], b[4*c+3]);
    }
}

extern "C" void kernel_launch(void* const* d_in, const int* in_sizes, int n_in,
                              void* d_out, int out_size, void* d_ws, size_t ws_size,
                              hipStream_t stream) {
    const float* prior = (const float*)d_in[0];
    const float* lik   = (const float*)d_in[1];
    const float* msg   = (const float*)d_in[2];
    const int B = in_sizes[0] / kD;          // 131072

    float* belief    = (float*)d_out;
    float* iters_out = belief + (size_t)B * kD;

    int*      flag   = (int*)d_ws;
    unsigned* slotsW = (unsigned*)d_ws + 16;
    unsigned* slotsF = slotsW + (kIters - 1) * kSlots;

    const int stride = B / (kSampleBlocks * 8);   // 4096 sampled rows

    bu_init<<<1, 256, 0, stream>>>((unsigned*)d_ws);
    bu_sample<<<kSampleBlocks, 256, 0, stream>>>(prior, lik, msg, slotsW, B, stride);
    bu_fast<<<B / 8, 256, 0, stream>>>(prior, lik, msg, belief, B);
    bu_resolve<<<1, 64, 0, stream>>>(slotsW, iters_out, flag);
    bu_full<<<2048, 256, 0, stream>>>(prior, lik, msg, belief, slotsF, flag, B);
    bu_fin<<<256, 256, 0, stream>>>(slotsF, prior, lik, msg, belief, iters_out, flag, B);
}

// Round 7
// 131.991 us; speedup vs baseline: 2.4805x; 1.0218x over previous
//
#include <hip/hip_runtime.h>

// BeliefUpdate. Identities:
//   b_{t+1} = softmax(log(b_t+eps)+log_lik) = normalize((b_t+eps)*W),
//   W = (lik+eps)(m0+eps)(m1+eps);  dropping inner +eps (~2.6e-8 rel err/iter):
//   b_10 = normalize(b_0 * W^10)  -- W^10 by squaring, ONE normalization.
// iters needs only a WITNESS row with change >= 1e-4 per t (lower bound of the
// global max proves "not converged"). R7: witness trajectory is computed by
// every 32nd block INSIDE the stream kernel (data already in registers, VALU
// 93% idle) -- no separate sample kernel, no extra traffic. Exact flag-guarded
// fallback preserves correctness if any sampled witness is below threshold.
// Measured walls (R0-R6): stream mixture (4 reads + NT write) runs at the same
// rate for 5 different schedules; VALU/occupancy/MLP are not levers.
// Atomic discipline (R5): ONE multi-lane atomic instruction per block max.

typedef float f32x4 __attribute__((ext_vector_type(4)));

static constexpr int   kD      = 256;
static constexpr float kEps    = 1e-10f;
static constexpr float kThresh = 1e-4f;
static constexpr int   kIters  = 10;
static constexpr int   kSlots  = 64;

template<int CTRL>
__device__ __forceinline__ float dpp_add(float v) {
    int t = __builtin_amdgcn_update_dpp(0, __float_as_int(v), CTRL, 0xf, 0xf, true);
    return v + __int_as_float(t);
}
template<int CTRL>
__device__ __forceinline__ float dpp_max(float v) {
    int t = __builtin_amdgcn_update_dpp(0, __float_as_int(v), CTRL, 0xf, 0xf, true);
    return fmaxf(v, __int_as_float(t));
}
__device__ __forceinline__ float swz_xor16(float v) {
    return __int_as_float(__builtin_amdgcn_ds_swizzle(__float_as_int(v), 0x401F));
}

// ws layout: [0] int flag; [16..] slotsW[9*64]; then slotsF[9*64]
__global__ __launch_bounds__(256) void bu_init(unsigned* __restrict__ ws) {
    for (int i = threadIdx.x; i < 16 + 2 * (kIters - 1) * kSlots; i += 256)
        ws[i] = 0u;
}

// ---- K1: stream kernel, witness fold-in on every 32nd block ------------
__global__ __launch_bounds__(256) void bu_fastW(
    const float* __restrict__ prior,
    const float* __restrict__ lik,
    const float* __restrict__ msg,
    float* __restrict__ belief,
    unsigned* __restrict__ slotsW,
    int B)
{
    const int tid  = threadIdx.x;
    const int wave = tid >> 6;
    const int lane = tid & 63;
    const int sub  = lane >> 5;
    const int q    = lane & 31;
    const int row  = (blockIdx.x * 4 + wave) * 2 + sub;
    const size_t off = (size_t)row * kD + (size_t)q * 8;

    const f32x4* pb = (const f32x4*)(prior + off);
    const f32x4* pl = (const f32x4*)(lik + off);
    const f32x4* p0 = (const f32x4*)(msg + off);
    const f32x4* p1 = (const f32x4*)(msg + (size_t)B * kD + off);

    f32x4 vb0 = pb[0], vb1 = pb[1];
    f32x4 vl0 = pl[0], vl1 = pl[1];
    f32x4 va0 = p0[0], va1 = p0[1];
    f32x4 vc0 = p1[0], vc1 = p1[1];

    float b0[8], W[8];
    #pragma unroll
    for (int k = 0; k < 4; ++k) {
        b0[k]     = vb0[k];
        b0[4 + k] = vb1[k];
        W[k]     = (vl0[k] + kEps) * (va0[k] + kEps) * (vc0[k] + kEps);
        W[4 + k] = (vl1[k] + kEps) * (va1[k] + kEps) * (vc1[k] + kEps);
    }

    // fast path: b10 = normalize(b0 * W^10), W^10 by squaring
    float u[8];
    #pragma unroll
    for (int j = 0; j < 8; ++j) {
        float W2 = W[j] * W[j], W4 = W2 * W2, W8 = W4 * W4;
        u[j] = b0[j] * (W8 * W2);
    }
    float s = ((u[0] + u[1]) + (u[2] + u[3])) + ((u[4] + u[5]) + (u[6] + u[7]));
    s = dpp_add<0x121>(s);
    s = dpp_add<0x122>(s);
    s = dpp_add<0x124>(s);
    s = dpp_add<0x128>(s);
    s += swz_xor16(s);
    const float inv = __builtin_amdgcn_rcpf(s);

    f32x4 o0 = {u[0] * inv, u[1] * inv, u[2] * inv, u[3] * inv};
    f32x4 o1 = {u[4] * inv, u[5] * inv, u[6] * inv, u[7] * inv};
    __builtin_nontemporal_store(o0, (f32x4*)(belief + off));
    __builtin_nontemporal_store(o1, (f32x4*)(belief + off) + 1);

    // witness trajectory: every 32nd block (4096 rows), zero extra traffic
    if ((blockIdx.x & 31) != 0) return;

    float t_u[8], pv[8];
    #pragma unroll
    for (int j = 0; j < 8; ++j) { t_u[j] = b0[j]; pv[j] = b0[j]; }

    float chg[kIters - 1];
    #pragma unroll
    for (int t = 0; t < kIters - 1; ++t) {   // only chg[0..8] gate iters
        #pragma unroll
        for (int j = 0; j < 8; ++j) t_u[j] *= W[j];
        float ts = ((t_u[0] + t_u[1]) + (t_u[2] + t_u[3]))
                 + ((t_u[4] + t_u[5]) + (t_u[6] + t_u[7]));
        ts = dpp_add<0x121>(ts);
        ts = dpp_add<0x122>(ts);
        ts = dpp_add<0x124>(ts);
        ts = dpp_add<0x128>(ts);
        ts += swz_xor16(ts);
        const float tinv = __builtin_amdgcn_rcpf(ts);
        float c = 0.f;
        #pragma unroll
        for (int j = 0; j < 8; ++j) {
            float nb = t_u[j] * tinv;
            c = fmaxf(c, fabsf(nb - pv[j]));
            pv[j] = nb;
        }
        chg[t] = c;
    }

    #pragma unroll
    for (int t = 0; t < kIters - 1; ++t) {
        float v = chg[t];
        v = dpp_max<0x121>(v);
        v = dpp_max<0x122>(v);
        v = dpp_max<0x124>(v);
        v = dpp_max<0x128>(v);
        v = fmaxf(v, swz_xor16(v));
        chg[t] = v;
    }
    __shared__ float schg[4][2][kIters - 1];
    if (q == 0) {
        #pragma unroll
        for (int t = 0; t < kIters - 1; ++t) schg[wave][sub][t] = chg[t];
    }
    __syncthreads();
    if (tid < kIters - 1) {
        float m = 0.f;
        #pragma unroll
        for (int w2 = 0; w2 < 4; ++w2) {
            m = fmaxf(m, schg[w2][0][tid]);
            m = fmaxf(m, schg[w2][1][tid]);
        }
        atomicMax(&slotsW[tid * kSlots + ((blockIdx.x >> 5) & (kSlots - 1))],
                  __float_as_uint(m));
    }
}

// ---- K2: decide from witnesses ----------------------------------------
__global__ __launch_bounds__(64) void bu_resolve(
    const unsigned* __restrict__ slotsW,
    float* __restrict__ iters_out,
    int* __restrict__ flag)
{
    const int lane = threadIdx.x & 63;
    bool allBig = true;
    #pragma unroll
    for (int t = 0; t < kIters - 1; ++t) {
        float v = __uint_as_float(slotsW[t * kSlots + lane]);
        #pragma unroll
        for (int o = 32; o > 0; o >>= 1) v = fmaxf(v, __shfl_xor(v, o));
        allBig = allBig && (v >= kThresh);
    }
    if (threadIdx.x == 0) {
        if (allBig) { *iters_out = (float)kIters; *flag = 0; }
        else        { *flag = 1; }
    }
}

// ---- K3: guarded full exact fallback -----------------------------------
__global__ __launch_bounds__(256) void bu_full(
    const float* __restrict__ prior,
    const float* __restrict__ lik,
    const float* __restrict__ msg,
    float* __restrict__ belief,
    unsigned* __restrict__ slotsF,
    const int* __restrict__ flag,
    int B)
{
    if (*flag == 0) return;
    const int tid  = threadIdx.x;
    const int wave = tid >> 6;
    const int lane = tid & 63;
    const int sub  = lane >> 5;
    const int q    = lane & 31;
    const int nUnits = B / 8;
    for (int unit = blockIdx.x; unit < nUnits; unit += gridDim.x) {
        const int row = (unit * 4 + wave) * 2 + sub;
        const size_t off = (size_t)row * kD + (size_t)q * 8;
        const f32x4* pb = (const f32x4*)(prior + off);
        const f32x4* pl = (const f32x4*)(lik + off);
        const f32x4* p0 = (const f32x4*)(msg + off);
        const f32x4* p1 = (const f32x4*)(msg + (size_t)B * kD + off);
        f32x4 vb0 = pb[0], vb1 = pb[1];
        f32x4 vl0 = pl[0], vl1 = pl[1];
        f32x4 va0 = p0[0], va1 = p0[1];
        f32x4 vc0 = p1[0], vc1 = p1[1];
        float u[8], W[8], pv[8];
        #pragma unroll
        for (int k = 0; k < 4; ++k) {
            u[k]     = vb0[k];
            u[4 + k] = vb1[k];
            W[k]     = (vl0[k] + kEps) * (va0[k] + kEps) * (vc0[k] + kEps);
            W[4 + k] = (vl1[k] + kEps) * (va1[k] + kEps) * (vc1[k] + kEps);
            pv[k]     = u[k];
            pv[4 + k] = u[4 + k];
        }
        float chg[kIters - 1];
        #pragma unroll
        for (int t = 0; t < kIters; ++t) {
            #pragma unroll
            for (int j = 0; j < 8; ++j) u[j] *= W[j];
            float s = ((u[0] + u[1]) + (u[2] + u[3])) + ((u[4] + u[5]) + (u[6] + u[7]));
            s = dpp_add<0x121>(s);
            s = dpp_add<0x122>(s);
            s = dpp_add<0x124>(s);
            s = dpp_add<0x128>(s);
            s += swz_xor16(s);
            const float inv = __builtin_amdgcn_rcpf(s);
            if (t < kIters - 1) {
                float c = 0.f;
                #pragma unroll
                for (int j = 0; j < 8; ++j) {
                    float nb = u[j] * inv;
                    c = fmaxf(c, fabsf(nb - pv[j]));
                    pv[j] = nb;
                }
                chg[t] = c;
            } else {
                #pragma unroll
                for (int j = 0; j < 8; ++j) pv[j] = u[j] * inv;
            }
        }
        f32x4 o0 = {pv[0], pv[1], pv[2], pv[3]};
        f32x4 o1 = {pv[4], pv[5], pv[6], pv[7]};
        __builtin_nontemporal_store(o0, (f32x4*)(belief + off));
        __builtin_nontemporal_store(o1, (f32x4*)(belief + off) + 1);

        #pragma unroll
        for (int t = 0; t < kIters - 1; ++t) {
            float v = chg[t];
            v = dpp_max<0x121>(v);
            v = dpp_max<0x122>(v);
            v = dpp_max<0x124>(v);
            v = dpp_max<0x128>(v);
            v = fmaxf(v, swz_xor16(v));
            v = fmaxf(v, __shfl_xor(v, 32));
            chg[t] = v;
        }
        __shared__ float schg[4][kIters - 1];
        if (lane == 0) {
            #pragma unroll
            for (int t = 0; t < kIters - 1; ++t) schg[wave][t] = chg[t];
        }
        __syncthreads();
        if (tid < kIters - 1) {
            float m = fmaxf(fmaxf(schg[0][tid], schg[1][tid]),
                            fmaxf(schg[2][tid], schg[3][tid]));
            atomicMax(&slotsF[tid * kSlots + (unit & (kSlots - 1))],
                      __float_as_uint(m));
        }
        __syncthreads();
    }
}

// ---- K4: guarded exact finalize + rare b_k recompute -------------------
__global__ __launch_bounds__(256) void bu_fin(
    const unsigned* __restrict__ slotsF,
    const float* __restrict__ prior,
    const float* __restrict__ lik,
    const float* __restrict__ msg,
    float* __restrict__ belief,
    float* __restrict__ iters_out,
    const int* __restrict__ flag,
    int B)
{
    if (*flag == 0) return;
    const int lane = threadIdx.x & 63;
    float chg[kIters - 1];
    #pragma unroll
    for (int t = 0; t < kIters - 1; ++t) {
        float v = __uint_as_float(slotsF[t * kSlots + lane]);
        #pragma unroll
        for (int o = 32; o > 0; o >>= 1) v = fmaxf(v, __shfl_xor(v, o));
        chg[t] = v;
    }
    int iters = 0;
    {
        bool done = false;
        #pragma unroll
        for (int t = 0; t < kIters; ++t) {
            if (!done) iters++;
            if (t < kIters - 1 && chg[t] < kThresh) done = true;
        }
    }
    if (blockIdx.x == 0 && threadIdx.x == 0) *iters_out = (float)iters;
    if (iters >= kIters) return;

    const int k    = iters;
    const int wave = threadIdx.x >> 6;
    const int g    = lane >> 4;
    const int q    = lane & 15;
    const int nUnits = B / 16;
    for (int u2 = blockIdx.x; u2 < nUnits; u2 += gridDim.x) {
        const int row = (u2 * 4 + wave) * 4 + g;
        const size_t off = (size_t)row * kD + (size_t)q * 16;
        const float* p0 = prior + off;
        const float* p1 = lik   + off;
        const float* p2 = msg   + off;
        const float* p3 = msg   + (size_t)B * kD + off;
        float b[16], W[16];
        #pragma unroll
        for (int c = 0; c < 4; ++c) {
            float4 vb = *(const float4*)(p0 + 4 * c);
            float4 vl = *(const float4*)(p1 + 4 * c);
            float4 v0 = *(const float4*)(p2 + 4 * c);
            float4 v1 = *(const float4*)(p3 + 4 * c);
            b[4*c+0] = vb.x; b[4*c+1] = vb.y; b[4*c+2] = vb.z; b[4*c+3] = vb.w;
            W[4*c+0] = (vl.x + kEps) * (v0.x + kEps) * (v1.x + kEps);
            W[4*c+1] = (vl.y + kEps) * (v0.y + kEps) * (v1.y + kEps);
            W[4*c+2] = (vl.z + kEps) * (v0.z + kEps) * (v1.z + kEps);
            W[4*c+3] = (vl.w + kEps) * (v0.w + kEps) * (v1.w + kEps);
        }
        for (int t = 0; t < k; ++t) {
            float pp[16];
            float s = 0.f;
            #pragma unroll
            for (int j = 0; j < 16; ++j) { pp[j] = (b[j] + kEps) * W[j]; s += pp[j]; }
            s += __shfl_xor(s, 1);
            s += __shfl_xor(s, 2);
            s += __shfl_xor(s, 4);
            s += __shfl_xor(s, 8);
            const float inv = 1.0f / s;
            #pragma unroll
            for (int j = 0; j < 16; ++j) b[j] = pp[j] * inv;
        }
        float* po = belief + off;
        #pragma unroll
        for (int c = 0; c < 4; ++c)
            *(float4*)(po + 4 * c) = make_float4(b[4*c], b[4*c+1], b[4*c+2], b[4*c+3]);
    }
}

extern "C" void kernel_launch(void* const* d_in, const int* in_sizes, int n_in,
                              void* d_out, int out_size, void* d_ws, size_t ws_size,
                              hipStream_t stream) {
    const float* prior = (const float*)d_in[0];
    const float* lik   = (const float*)d_in[1];
    const float* msg   = (const float*)d_in[2];
    const int B = in_sizes[0] / kD;          // 131072

    float* belief    = (float*)d_out;
    float* iters_out = belief + (size_t)B * kD;

    int*      flag   = (int*)d_ws;
    unsigned* slotsW = (unsigned*)d_ws + 16;
    unsigned* slotsF = slotsW + (kIters - 1) * kSlots;

    bu_init<<<1, 256, 0, stream>>>((unsigned*)d_ws);
    bu_fastW<<<B / 8, 256, 0, stream>>>(prior, lik, msg, belief, slotsW, B);
    bu_resolve<<<1, 64, 0, stream>>>(slotsW, iters_out, flag);
    bu_full<<<2048, 256, 0, stream>>>(prior, lik, msg, belief, slotsF, flag, B);
    bu_fin<<<256, 256, 0, stream>>>(slotsF, prior, lik, msg, belief, iters_out, flag, B);
}

// Round 8
// 106.532 us; speedup vs baseline: 3.0733x; 1.2390x over previous
//
#include <hip/hip_runtime.h>

// BeliefUpdate. Identities:
//   b_{t+1} = softmax(log(b_t+eps)+log_lik) = normalize((b_t+eps)*W),
//   W = (lik+eps)(m0+eps)(m1+eps);  dropping inner +eps (~2.6e-8 rel err/iter):
//   b_10 = normalize(b_0 * W^10)  -- W^10 by squaring, ONE normalization.
// iters needs only WITNESS rows with change >= 1e-4 per t; every 32nd block
// runs the 9-step trajectory on data already in registers and plain-stores its
// 9 maxima to a private slot (all slots written every call -> no init, no
// atomics). bu_full/bu_fin re-derive the decision from the 18 KB slot array
// (L2-hit) -- flag-free, 3 dispatches total.
// R8 experiment: NT-load msg (268 MB, exceeds L3 alone) so it streams pure-HBM
// without allocating; L3 then holds prior+lik (~268 MB) across replays --
// un-interleaving L3 hits from HBM misses.
// Measured walls (R0-R7): stream rate identical for 6 schedules; VALU/
// occupancy/MLP are not levers. Atomic discipline (R5): bursts of scalar
// atomics cost +150us -- keep zero atomics.

typedef float f32x4 __attribute__((ext_vector_type(4)));

static constexpr int   kD      = 256;
static constexpr float kEps    = 1e-10f;
static constexpr float kThresh = 1e-4f;
static constexpr int   kIters  = 10;
static constexpr int   kWSlots = 512;   // witness blocks (16384/32)
static constexpr int   kFSlots = 512;   // fallback blocks

template<int CTRL>
__device__ __forceinline__ float dpp_add(float v) {
    int t = __builtin_amdgcn_update_dpp(0, __float_as_int(v), CTRL, 0xf, 0xf, true);
    return v + __int_as_float(t);
}
template<int CTRL>
__device__ __forceinline__ float dpp_max(float v) {
    int t = __builtin_amdgcn_update_dpp(0, __float_as_int(v), CTRL, 0xf, 0xf, true);
    return fmaxf(v, __int_as_float(t));
}
__device__ __forceinline__ float swz_xor16(float v) {
    return __int_as_float(__builtin_amdgcn_ds_swizzle(__float_as_int(v), 0x401F));
}
__device__ __forceinline__ float wave_max64(float v) {
    v = dpp_max<0x121>(v);
    v = dpp_max<0x122>(v);
    v = dpp_max<0x124>(v);
    v = dpp_max<0x128>(v);
    v = fmaxf(v, swz_xor16(v));
    v = fmaxf(v, __shfl_xor(v, 32));
    return v;
}

// Uniform block-wide decision from the witness slots (L2-hit reads).
__device__ __forceinline__ bool slotsW_allBig(const float* __restrict__ slotsW) {
    __shared__ int s_ok;
    const int tid = threadIdx.x;
    if (tid == 0) s_ok = 1;
    __syncthreads();
    if (tid < 64) {
        bool ok = true;
        #pragma unroll
        for (int t = 0; t < kIters - 1; ++t) {
            float v = 0.f;
            #pragma unroll
            for (int k = 0; k < kWSlots / 64; ++k)
                v = fmaxf(v, slotsW[t * kWSlots + k * 64 + tid]);
            v = wave_max64(v);
            ok = ok && (v >= kThresh);
        }
        if (tid == 0 && !ok) s_ok = 0;
    }
    __syncthreads();
    return s_ok != 0;
}

// ---- K1: stream kernel + witness fold-in on every 32nd block -----------
__global__ __launch_bounds__(256) void bu_fastW(
    const float* __restrict__ prior,
    const float* __restrict__ lik,
    const float* __restrict__ msg,
    float* __restrict__ belief,
    float* __restrict__ slotsW,
    int B)
{
    const int tid  = threadIdx.x;
    const int wave = tid >> 6;
    const int lane = tid & 63;
    const int sub  = lane >> 5;
    const int q    = lane & 31;
    const int row  = (blockIdx.x * 4 + wave) * 2 + sub;
    const size_t off = (size_t)row * kD + (size_t)q * 8;

    const f32x4* pb = (const f32x4*)(prior + off);
    const f32x4* pl = (const f32x4*)(lik + off);
    const f32x4* p0 = (const f32x4*)(msg + off);
    const f32x4* p1 = (const f32x4*)(msg + (size_t)B * kD + off);

    f32x4 vb0 = pb[0], vb1 = pb[1];
    f32x4 vl0 = pl[0], vl1 = pl[1];
    // msg: NT loads -- stream from HBM without L3 allocation (268 MB > L3);
    // leaves L3 to keep prior+lik resident across replays.
    f32x4 va0 = __builtin_nontemporal_load(p0);
    f32x4 va1 = __builtin_nontemporal_load(p0 + 1);
    f32x4 vc0 = __builtin_nontemporal_load(p1);
    f32x4 vc1 = __builtin_nontemporal_load(p1 + 1);

    float b0[8], W[8];
    #pragma unroll
    for (int k = 0; k < 4; ++k) {
        b0[k]     = vb0[k];
        b0[4 + k] = vb1[k];
        W[k]     = (vl0[k] + kEps) * (va0[k] + kEps) * (vc0[k] + kEps);
        W[4 + k] = (vl1[k] + kEps) * (va1[k] + kEps) * (vc1[k] + kEps);
    }

    // fast path: b10 = normalize(b0 * W^10), W^10 by squaring
    float u[8];
    #pragma unroll
    for (int j = 0; j < 8; ++j) {
        float W2 = W[j] * W[j], W4 = W2 * W2, W8 = W4 * W4;
        u[j] = b0[j] * (W8 * W2);
    }
    float s = ((u[0] + u[1]) + (u[2] + u[3])) + ((u[4] + u[5]) + (u[6] + u[7]));
    s = dpp_add<0x121>(s);
    s = dpp_add<0x122>(s);
    s = dpp_add<0x124>(s);
    s = dpp_add<0x128>(s);
    s += swz_xor16(s);
    const float inv = __builtin_amdgcn_rcpf(s);

    f32x4 o0 = {u[0] * inv, u[1] * inv, u[2] * inv, u[3] * inv};
    f32x4 o1 = {u[4] * inv, u[5] * inv, u[6] * inv, u[7] * inv};
    __builtin_nontemporal_store(o0, (f32x4*)(belief + off));
    __builtin_nontemporal_store(o1, (f32x4*)(belief + off) + 1);

    // witness trajectory: every 32nd block (4096 rows), zero extra traffic
    if ((blockIdx.x & 31) != 0) return;

    float t_u[8], pv[8];
    #pragma unroll
    for (int j = 0; j < 8; ++j) { t_u[j] = b0[j]; pv[j] = b0[j]; }

    float chg[kIters - 1];
    #pragma unroll
    for (int t = 0; t < kIters - 1; ++t) {   // only chg[0..8] gate iters
        #pragma unroll
        for (int j = 0; j < 8; ++j) t_u[j] *= W[j];
        float ts = ((t_u[0] + t_u[1]) + (t_u[2] + t_u[3]))
                 + ((t_u[4] + t_u[5]) + (t_u[6] + t_u[7]));
        ts = dpp_add<0x121>(ts);
        ts = dpp_add<0x122>(ts);
        ts = dpp_add<0x124>(ts);
        ts = dpp_add<0x128>(ts);
        ts += swz_xor16(ts);
        const float tinv = __builtin_amdgcn_rcpf(ts);
        float c = 0.f;
        #pragma unroll
        for (int j = 0; j < 8; ++j) {
            float nb = t_u[j] * tinv;
            c = fmaxf(c, fabsf(nb - pv[j]));
            pv[j] = nb;
        }
        chg[t] = c;
    }

    #pragma unroll
    for (int t = 0; t < kIters - 1; ++t) {
        float v = chg[t];
        v = dpp_max<0x121>(v);
        v = dpp_max<0x122>(v);
        v = dpp_max<0x124>(v);
        v = dpp_max<0x128>(v);
        v = fmaxf(v, swz_xor16(v));
        chg[t] = v;   // max within 32-lane group
    }
    __shared__ float schg[4][2][kIters - 1];
    if (q == 0) {
        #pragma unroll
        for (int t = 0; t < kIters - 1; ++t) schg[wave][sub][t] = chg[t];
    }
    __syncthreads();
    if (tid < kIters - 1) {
        float m = 0.f;
        #pragma unroll
        for (int w2 = 0; w2 < 4; ++w2) {
            m = fmaxf(m, schg[w2][0][tid]);
            m = fmaxf(m, schg[w2][1][tid]);
        }
        // private slot: plain store, no atomic, no init required
        slotsW[tid * kWSlots + (blockIdx.x >> 5)] = m;
    }
}

// ---- K2: guarded full exact fallback (a.s. never runs) -----------------
__global__ __launch_bounds__(256) void bu_full(
    const float* __restrict__ prior,
    const float* __restrict__ lik,
    const float* __restrict__ msg,
    float* __restrict__ belief,
    const float* __restrict__ slotsW,
    float* __restrict__ slotsF,
    int B)
{
    if (slotsW_allBig(slotsW)) return;

    const int tid  = threadIdx.x;
    const int wave = tid >> 6;
    const int lane = tid & 63;
    const int sub  = lane >> 5;
    const int q    = lane & 31;
    const int nUnits = B / 8;

    float chgAcc[kIters - 1];
    #pragma unroll
    for (int t = 0; t < kIters - 1; ++t) chgAcc[t] = 0.f;

    for (int unit = blockIdx.x; unit < nUnits; unit += gridDim.x) {
        const int row = (unit * 4 + wave) * 2 + sub;
        const size_t off = (size_t)row * kD + (size_t)q * 8;
        const f32x4* pb = (const f32x4*)(prior + off);
        const f32x4* pl = (const f32x4*)(lik + off);
        const f32x4* p0 = (const f32x4*)(msg + off);
        const f32x4* p1 = (const f32x4*)(msg + (size_t)B * kD + off);
        f32x4 vb0 = pb[0], vb1 = pb[1];
        f32x4 vl0 = pl[0], vl1 = pl[1];
        f32x4 va0 = p0[0], va1 = p0[1];
        f32x4 vc0 = p1[0], vc1 = p1[1];
        float u[8], W[8], pv[8];
        #pragma unroll
        for (int k = 0; k < 4; ++k) {
            u[k]     = vb0[k];
            u[4 + k] = vb1[k];
            W[k]     = (vl0[k] + kEps) * (va0[k] + kEps) * (vc0[k] + kEps);
            W[4 + k] = (vl1[k] + kEps) * (va1[k] + kEps) * (vc1[k] + kEps);
            pv[k]     = u[k];
            pv[4 + k] = u[4 + k];
        }
        #pragma unroll
        for (int t = 0; t < kIters; ++t) {
            #pragma unroll
            for (int j = 0; j < 8; ++j) u[j] *= W[j];
            float s = ((u[0] + u[1]) + (u[2] + u[3])) + ((u[4] + u[5]) + (u[6] + u[7]));
            s = dpp_add<0x121>(s);
            s = dpp_add<0x122>(s);
            s = dpp_add<0x124>(s);
            s = dpp_add<0x128>(s);
            s += swz_xor16(s);
            const float inv = __builtin_amdgcn_rcpf(s);
            if (t < kIters - 1) {
                float c = 0.f;
                #pragma unroll
                for (int j = 0; j < 8; ++j) {
                    float nb = u[j] * inv;
                    c = fmaxf(c, fabsf(nb - pv[j]));
                    pv[j] = nb;
                }
                chgAcc[t] = fmaxf(chgAcc[t], c);
            } else {
                #pragma unroll
                for (int j = 0; j < 8; ++j) pv[j] = u[j] * inv;
            }
        }
        f32x4 o0 = {pv[0], pv[1], pv[2], pv[3]};
        f32x4 o1 = {pv[4], pv[5], pv[6], pv[7]};
        __builtin_nontemporal_store(o0, (f32x4*)(belief + off));
        __builtin_nontemporal_store(o1, (f32x4*)(belief + off) + 1);
    }

    // block-wide reduce, one private slot per block per t (plain stores)
    #pragma unroll
    for (int t = 0; t < kIters - 1; ++t) chgAcc[t] = wave_max64(chgAcc[t]);
    __shared__ float schg[4][kIters - 1];
    if (lane == 0) {
        #pragma unroll
        for (int t = 0; t < kIters - 1; ++t) schg[wave][t] = chgAcc[t];
    }
    __syncthreads();
    if (tid < kIters - 1) {
        float m = fmaxf(fmaxf(schg[0][tid], schg[1][tid]),
                        fmaxf(schg[2][tid], schg[3][tid]));
        slotsF[tid * kFSlots + blockIdx.x] = m;
    }
}

// ---- K3: finalize (writes iters; rare b_k recompute) --------------------
__global__ __launch_bounds__(256) void bu_fin(
    const float* __restrict__ slotsW,
    const float* __restrict__ slotsF,
    const float* __restrict__ prior,
    const float* __restrict__ lik,
    const float* __restrict__ msg,
    float* __restrict__ belief,
    float* __restrict__ iters_out,
    int B)
{
    if (slotsW_allBig(slotsW)) {
        if (blockIdx.x == 0 && threadIdx.x == 0) *iters_out = (float)kIters;
        return;
    }

    // exact iters from fallback slots
    __shared__ int s_it;
    const int tid  = threadIdx.x;
    if (tid < 64) {
        float chg[kIters - 1];
        #pragma unroll
        for (int t = 0; t < kIters - 1; ++t) {
            float v = 0.f;
            #pragma unroll
            for (int k = 0; k < kFSlots / 64; ++k)
                v = fmaxf(v, slotsF[t * kFSlots + k * 64 + tid]);
            chg[t] = wave_max64(v);
        }
        if (tid == 0) {
            int iters = 0;
            bool done = false;
            #pragma unroll
            for (int t = 0; t < kIters; ++t) {
                if (!done) iters++;
                if (t < kIters - 1 && chg[t] < kThresh) done = true;
            }
            s_it = iters;
        }
    }
    __syncthreads();
    const int iters = s_it;
    if (blockIdx.x == 0 && tid == 0) *iters_out = (float)iters;
    if (iters >= kIters) return;   // b_10 from bu_full is already correct

    const int k    = iters;
    const int lane = tid & 63;
    const int wave = tid >> 6;
    const int g    = lane >> 4;
    const int q    = lane & 15;
    const int nUnits = B / 16;
    for (int u2 = blockIdx.x; u2 < nUnits; u2 += gridDim.x) {
        const int row = (u2 * 4 + wave) * 4 + g;
        const size_t off = (size_t)row * kD + (size_t)q * 16;
        const float* p0 = prior + off;
        const float* p1 = lik   + off;
        const float* p2 = msg   + off;
        const float* p3 = msg   + (size_t)B * kD + off;
        float b[16], W[16];
        #pragma unroll
        for (int c = 0; c < 4; ++c) {
            float4 vb = *(const float4*)(p0 + 4 * c);
            float4 vl = *(const float4*)(p1 + 4 * c);
            float4 v0 = *(const float4*)(p2 + 4 * c);
            float4 v1 = *(const float4*)(p3 + 4 * c);
            b[4*c+0] = vb.x; b[4*c+1] = vb.y; b[4*c+2] = vb.z; b[4*c+3] = vb.w;
            W[4*c+0] = (vl.x + kEps) * (v0.x + kEps) * (v1.x + kEps);
            W[4*c+1] = (vl.y + kEps) * (v0.y + kEps) * (v1.y + kEps);
            W[4*c+2] = (vl.z + kEps) * (v0.z + kEps) * (v1.z + kEps);
            W[4*c+3] = (vl.w + kEps) * (v0.w + kEps) * (v1.w + kEps);
        }
        for (int t = 0; t < k; ++t) {
            float pp[16];
            float s = 0.f;
            #pragma unroll
            for (int j = 0; j < 16; ++j) { pp[j] = (b[j] + kEps) * W[j]; s += pp[j]; }
            s += __shfl_xor(s, 1);
            s += __shfl_xor(s, 2);
            s += __shfl_xor(s, 4);
            s += __shfl_xor(s, 8);
            const float inv = 1.0f / s;
            #pragma unroll
            for (int j = 0; j < 16; ++j) b[j] = pp[j] * inv;
        }
        float* po = belief + off;
        #pragma unroll
        for (int c = 0; c < 4; ++c)
            *(float4*)(po + 4 * c) = make_float4(b[4*c], b[4*c+1], b[4*c+2], b[4*c+3]);
    }
}

extern "C" void kernel_launch(void* const* d_in, const int* in_sizes, int n_in,
                              void* d_out, int out_size, void* d_ws, size_t ws_size,
                              hipStream_t stream) {
    const float* prior = (const float*)d_in[0];
    const float* lik   = (const float*)d_in[1];
    const float* msg   = (const float*)d_in[2];
    const int B = in_sizes[0] / kD;          // 131072

    float* belief    = (float*)d_out;
    float* iters_out = belief + (size_t)B * kD;

    float* slotsW = (float*)d_ws;                          // 9*512 floats
    float* slotsF = slotsW + (kIters - 1) * kWSlots;       // 9*512 floats

    bu_fastW<<<B / 8, 256, 0, stream>>>(prior, lik, msg, belief, slotsW, B);
    bu_full<<<kFSlots, 256, 0, stream>>>(prior, lik, msg, belief, slotsW, slotsF, B);
    bu_fin<<<256, 256, 0, stream>>>(slotsW, slotsF, prior, lik, msg, belief,
                                    iters_out, B);
}